// Round 1
// baseline (103.612 us; speedup 1.0000x reference)
//
#include <hip/hip_runtime.h>

#define DIMS 64
#define KCB 512
#define OUT_Q 8388608   // 32*64*64*64
#define MAIN_WGS 512

typedef float f32x4 __attribute__((ext_vector_type(4)));
typedef float f4    __attribute__((ext_vector_type(4)));
typedef short short8 __attribute__((ext_vector_type(8)));

// ws layout (bytes):
//   [0..4)      float   loss sum accumulator
//   [4..8)      uint    WG completion counter
//   [16..2064)  float   neg_half_c2[512]  (= -0.5*||c_k||^2)
//   [4096..69632) short bf16 codebook [512][64]

static __device__ __forceinline__ unsigned short f2bf(float f) {
    unsigned int u = __float_as_uint(f);
    unsigned int r = u + 0x7FFFu + ((u >> 16) & 1u);   // RNE
    return (unsigned short)(r >> 16);
}

__global__ void vq_prep(const float* __restrict__ cb, float* __restrict__ ws) {
    int t = blockIdx.x * blockDim.x + threadIdx.x;   // 0..511 = codebook row
    if (t == 0) { ws[0] = 0.0f; ((unsigned int*)ws)[1] = 0u; }
    if (t >= KCB) return;
    const f4* row = (const f4*)(cb + t * DIMS);
    unsigned int* dst = (unsigned int*)((char*)ws + 4096) + t * (DIMS / 2);
    float s = 0.0f;
#pragma unroll
    for (int i = 0; i < DIMS / 4; ++i) {
        f4 v = row[i];
        s += v[0]*v[0] + v[1]*v[1] + v[2]*v[2] + v[3]*v[3];
        unsigned int lo = ((unsigned int)f2bf(v[1]) << 16) | f2bf(v[0]);
        unsigned int hi = ((unsigned int)f2bf(v[3]) << 16) | f2bf(v[2]);
        dst[i * 2]     = lo;
        dst[i * 2 + 1] = hi;
    }
    ws[4 + t] = -0.5f * s;
}

__global__ __launch_bounds__(256) void vq_main(const float* __restrict__ x,
                                               const float* __restrict__ cb,
                                               float* __restrict__ out,
                                               float* __restrict__ ws) {
    const int lane = threadIdx.x & 63;
    const int wid  = threadIdx.x >> 6;
    const int iter = blockIdx.x * 4 + wid;        // 0..2047
    const long rowbase = (long)iter * 64;         // 64 x-rows per wave
    const int r15 = lane & 15;
    const int g   = lane >> 4;

    // ---- A fragments: 4 tiles x 2 K-halves; lane holds A[row=r15][k=g*8+i(+32h)]
    short8 A[4][2];
    const float* xa = x + (rowbase + r15) * DIMS + g * 8;
#pragma unroll
    for (int t = 0; t < 4; ++t) {
#pragma unroll
        for (int h = 0; h < 2; ++h) {
            const f4* p = (const f4*)(xa + t * 16 * DIMS + h * 32);
            f4 u0 = p[0], u1 = p[1];
            short8 fr;
            fr[0] = (short)f2bf(u0[0]); fr[1] = (short)f2bf(u0[1]);
            fr[2] = (short)f2bf(u0[2]); fr[3] = (short)f2bf(u0[3]);
            fr[4] = (short)f2bf(u1[0]); fr[5] = (short)f2bf(u1[1]);
            fr[6] = (short)f2bf(u1[2]); fr[7] = (short)f2bf(u1[3]);
            A[t][h] = fr;
        }
    }

    const short* cbbf = (const short*)((const char*)ws + 4096);
    const float* nhc2 = ws + 4;

    float bv[4][4];
    int   bk[4][4];
#pragma unroll
    for (int t = 0; t < 4; ++t)
#pragma unroll
        for (int j = 0; j < 4; ++j) { bv[t][j] = -3.4e38f; bk[t][j] = 0; }

    // ---- score all 512 codebook entries: 32 k-tiles of 16
#pragma unroll 4
    for (int kt = 0; kt < 32; ++kt) {
        const int krow = kt * 16 + r15;           // lane's codebook row (D-col of scores)
        float ic = nhc2[krow];
        const short* bbase = cbbf + krow * DIMS + g * 8;
        short8 b0 = *(const short8*)(bbase);
        short8 b1 = *(const short8*)(bbase + 32);
        f32x4 init = {ic, ic, ic, ic};
#pragma unroll
        for (int t = 0; t < 4; ++t) {
            f32x4 acc = __builtin_amdgcn_mfma_f32_16x16x32_bf16(A[t][0], b0, init, 0, 0, 0);
            acc       = __builtin_amdgcn_mfma_f32_16x16x32_bf16(A[t][1], b1, acc,  0, 0, 0);
            // D layout: lane holds rows g*4+j, col = r15 -> candidate k = krow
#pragma unroll
            for (int j = 0; j < 4; ++j) {
                if (acc[j] > bv[t][j]) { bv[t][j] = acc[j]; bk[t][j] = krow; }
            }
        }
    }

    // ---- argmax reduce across the 16 lanes of each row-group (k dimension)
#pragma unroll
    for (int s = 0; s < 4; ++s) {
#pragma unroll
        for (int t = 0; t < 4; ++t) {
#pragma unroll
            for (int j = 0; j < 4; ++j) {
                float ov = __shfl_xor(bv[t][j], 1 << s, 64);
                int   ok = __shfl_xor(bk[t][j], 1 << s, 64);
                if (ov > bv[t][j] || (ov == bv[t][j] && ok < bk[t][j])) {
                    bv[t][j] = ov; bk[t][j] = ok;
                }
            }
        }
    }
    // now every lane in group g holds idx for rows g*4+j (j=0..3) of each tile

    // ---- epilogue: gather codebook rows (fp32), write out, accumulate loss
    const int orow = lane >> 2;        // 0..15: row within tile; its group == g
    const int cseg = lane & 3;         // 16-float column segment
    const int j2   = orow & 3;
    float lsum = 0.0f;
#pragma unroll
    for (int t = 0; t < 4; ++t) {
        int idx = bk[t][0];
        if (j2 == 1) idx = bk[t][1];
        if (j2 == 2) idx = bk[t][2];
        if (j2 == 3) idx = bk[t][3];
        const long row = rowbase + t * 16 + orow;
        const f4* cq = (const f4*)(cb + (long)idx * DIMS + cseg * 16);
        const f4* xr = (const f4*)(x + row * DIMS + cseg * 16);
        f4* op       = (f4*)(out + row * DIMS + cseg * 16);
#pragma unroll
        for (int u = 0; u < 4; ++u) {
            f4 q = cq[u];
            f4 xv = xr[u];
            op[u] = q;
            f4 d = q - xv;
            lsum += d[0]*d[0] + d[1]*d[1] + d[2]*d[2] + d[3]*d[3];
        }
    }

    // ---- loss: wave reduce -> WG reduce -> one atomic per WG -> last WG writes
#pragma unroll
    for (int s = 0; s < 6; ++s) lsum += __shfl_xor(lsum, 1 << s, 64);
    __shared__ float wsum[4];
    if (lane == 0) wsum[wid] = lsum;
    __syncthreads();
    if (threadIdx.x == 0) {
        float tot = wsum[0] + wsum[1] + wsum[2] + wsum[3];
        atomicAdd(ws, tot);
        __threadfence();
        unsigned int ticket = atomicAdd((unsigned int*)ws + 1, 1u);
        if (ticket == MAIN_WGS - 1) {
            float total = atomicAdd(ws, 0.0f);   // coherent read of final sum
            out[OUT_Q] = 1.25f * total / 8388608.0f;
        }
    }
}

extern "C" void kernel_launch(void* const* d_in, const int* in_sizes, int n_in,
                              void* d_out, int out_size, void* d_ws, size_t ws_size,
                              hipStream_t stream) {
    const float* x  = (const float*)d_in[0];
    const float* cb = (const float*)d_in[1];
    float* out = (float*)d_out;
    float* ws  = (float*)d_ws;
    vq_prep<<<2, 256, 0, stream>>>(cb, ws);
    vq_main<<<MAIN_WGS, 256, 0, stream>>>(x, cb, out, ws);
}